// Round 5
// baseline (81.877 us; speedup 1.0000x reference)
//
#include <hip/hip_runtime.h>

#define HH 256
#define WW 256
#define NPIX (HH*WW)
#define NBATCH 4
#define RPB 4              // P-rows owned per block
#define HALO 6             // max 45-degree displacement
#define LROWS (RPB+HALO)   // 10 rows of moments in LDS
#define NBX (HH/RPB)       // 64 blocks_x
#define NPAIR 32           // 8 combos * 4 batches
#define NBLK (NBX*NBATCH)  // 256 blocks
#define MAGIC 0x13579BDFu

// Closed-form level moments for centers = linspace(-1,1,256), sigma = 0.5.
// s0 = sum_j exp(-2(x-c_j)^2), s1 = sum_j j*e_j, s2 = sum_j j^2*e_j.
// Uniform-grid Gaussian sums == midpoint-rule integrals to O(step^2) ~ 6e-5 rel.
__device__ __forceinline__ void moments(float xv, float& s0, float& s1, float& s2) {
    const float h    = 1.0f / 255.0f;      // step/2
    const float invS = 127.5f;             // 1/step
    const float K    = 0.626657068658f;    // sqrt(pi/8)
    const float SQ2  = 1.41421356237f;

    float u1 = (1.0f + h) - xv;
    float u0 = (-1.0f - h) - xv;
    float A  = SQ2 * u1;
    float B  = SQ2 * u0;

    float I0 = K * (erff(A) - erff(B));
    float eA = __expf(-A * A);
    float eB = __expf(-B * B);
    float I1 = 0.25f * (eB - eA);
    float I2 = 0.25f * (u0 * eB - u1 * eA) + 0.25f * I0;

    float S0  = invS * I0;
    float Sc  = invS * fmaf(xv, I0, I1);
    float Scc = invS * (xv * xv * I0 + 2.0f * xv * I1 + I2);

    s0 = S0;
    s1 = invS * (Sc + S0);
    s2 = invS * invS * (Scc + 2.0f * Sc + S0);
}

// Single launch: tile moments -> LDS -> 8 (theta,d) pair sums -> partials,
// then flag-based last-block finalize (no second kernel).
// combos 0..3: theta=0,  d={1,3,5,7}: Q=(r, w+d),   valid w<W-d
// combos 4..7: theta=45, d={1,2,4,6}: Q=(r-d, w+d), valid r>=d && w<W-d
__global__ __launch_bounds__(256) void fused_kernel(const float* __restrict__ x,
                                                    float* __restrict__ part,
                                                    unsigned* __restrict__ flags,
                                                    float* __restrict__ out) {
    __shared__ float ls0[LROWS][WW];
    __shared__ float ls1[LROWS][WW];
    __shared__ float ls2[LROWS][WW];
    __shared__ float sred[4][16];
    __shared__ int okw[4];

    const int w     = threadIdx.x;          // column (lane = column -> stride-1 LDS)
    const int bx    = blockIdx.x;
    const int batch = blockIdx.y;
    const int bid   = batch * NBX + bx;
    const int r0    = bx * RPB;
    const float* xb = x + batch * NPIX;

    #pragma unroll
    for (int i = 0; i < LROWS; ++i) {
        int g = r0 - HALO + i;
        float s0 = 0.f, s1 = 0.f, s2 = 0.f;
        if (g >= 0) moments(xb[g * WW + w], s0, s1, s2);
        ls0[i][w] = s0; ls1[i][w] = s1; ls2[i][w] = s2;
    }
    __syncthreads();

    const int d0t[4]  = {1, 3, 5, 7};
    const int d45t[4] = {1, 2, 4, 6};
    float num[8] = {0,0,0,0,0,0,0,0};
    float den[8] = {0,0,0,0,0,0,0,0};

    #pragma unroll
    for (int rr = 0; rr < RPB; ++rr) {
        int lr = rr + HALO;
        int r  = r0 + rr;
        float P0 = ls0[lr][w], P1 = ls1[lr][w], P2 = ls2[lr][w];
        #pragma unroll
        for (int k = 0; k < 4; ++k) {
            int d = d0t[k];
            if (w < WW - d) {
                float Q0 = ls0[lr][w + d], Q1 = ls1[lr][w + d], Q2 = ls2[lr][w + d];
                den[k] = fmaf(P0, Q0, den[k]);
                num[k] = fmaf(P2, Q0, num[k]);
                num[k] = fmaf(P0, Q2, num[k]);
                num[k] = fmaf(-2.0f * P1, Q1, num[k]);
            }
        }
        #pragma unroll
        for (int k = 0; k < 4; ++k) {
            int d = d45t[k];
            if (r >= d && w < WW - d) {
                float Q0 = ls0[lr - d][w + d], Q1 = ls1[lr - d][w + d], Q2 = ls2[lr - d][w + d];
                den[k + 4] = fmaf(P0, Q0, den[k + 4]);
                num[k + 4] = fmaf(P2, Q0, num[k + 4]);
                num[k + 4] = fmaf(P0, Q2, num[k + 4]);
                num[k + 4] = fmaf(-2.0f * P1, Q1, num[k + 4]);
            }
        }
    }

    // wave(64) butterfly, then cross-wave combine via LDS
    #pragma unroll
    for (int off = 32; off > 0; off >>= 1) {
        #pragma unroll
        for (int k = 0; k < 8; ++k) {
            num[k] += __shfl_down(num[k], off);
            den[k] += __shfl_down(den[k], off);
        }
    }
    int lane = threadIdx.x & 63, wave = threadIdx.x >> 6;
    if (lane == 0) {
        #pragma unroll
        for (int k = 0; k < 8; ++k) { sred[wave][k] = num[k]; sred[wave][k + 8] = den[k]; }
    }
    __syncthreads();
    if (threadIdx.x < 16) {
        int k = threadIdx.x;
        float v = sred[0][k] + sred[1][k] + sred[2][k] + sred[3][k];
        int pair = (k & 7) * 4 + batch;
        int off  = (k < 8) ? 0 : NPAIR * NBX;
        part[off + pair * NBX + bx] = v;
        __threadfence();   // drain this thread's partial store toward the coherence point
    }
    __syncthreads();

    // Publish arrival: release makes this block's partials visible agent-wide.
    if (threadIdx.x == 0) {
        __hip_atomic_store(&flags[bid], MAGIC, __ATOMIC_RELEASE, __HIP_MEMORY_SCOPE_AGENT);
        __threadfence();   // our flag is globally performed before we scan others
    }
    __syncthreads();

    // Scan all 256 flags; the wall-clock-last block is guaranteed to see all set.
    unsigned f = __hip_atomic_load(&flags[threadIdx.x], __ATOMIC_ACQUIRE, __HIP_MEMORY_SCOPE_AGENT);
    unsigned long long b = __ballot(f == MAGIC);
    if (lane == 0) okw[wave] = (b == ~0ull) ? 1 : 0;
    __syncthreads();
    if (!(okw[0] & okw[1] & okw[2] & okw[3])) return;

    // Finalizer (>=1 block; duplicates write identical values — benign).
    if (threadIdx.x < 64) {
        int n = threadIdx.x;          // n = combo*4 + batch
        float v;
        if ((n >> 2) < 8) {
            float nu = 0.f, de = 0.f;
            #pragma unroll 8
            for (int bb = 0; bb < NBX; ++bb) {
                nu += part[n * NBX + bb];
                de += part[NPAIR * NBX + n * NBX + bb];
            }
            v = nu / de;
        } else {
            // centers_b all -1 -> all bins equal -> contrast = sum_{jk}(j-k)^2 / L^2
            v = (float)(715816960.0 / 65536.0);   // 10922.65625
        }
        out[n] = v;
    }
}

extern "C" void kernel_launch(void* const* d_in, const int* in_sizes, int n_in,
                              void* d_out, int out_size, void* d_ws, size_t ws_size,
                              hipStream_t stream) {
    const float* x = (const float*)d_in[0];
    float* out = (float*)d_out;
    float* part     = (float*)d_ws;                    // 2*NPAIR*NBX floats = 16 KiB
    unsigned* flags = (unsigned*)((float*)d_ws + 2 * NPAIR * NBX);  // 256 u32
    // flags start as harness poison (0xAAAAAAAA) or any value != MAGIC; each
    // launch every block overwrites its own flag before anyone can finalize.

    dim3 g1(NBX, NBATCH);
    fused_kernel<<<g1, 256, 0, stream>>>(x, part, flags, out);
}

// Round 6
// 62.802 us; speedup vs baseline: 1.3037x; 1.3037x over previous
//
#include <hip/hip_runtime.h>

#define HH 256
#define WW 256
#define NPIX (HH*WW)
#define NBATCH 4
#define RPB 4              // P-rows owned per block
#define HALO 6             // max 45-degree displacement
#define LROWS (RPB+HALO)   // 10 rows of moments in LDS
#define NBX (HH/RPB)       // 64 blocks_x
#define NPAIR 32           // 8 combos * 4 batches

// Closed-form level moments for centers = linspace(-1,1,256), sigma = 0.5.
// s0 = sum_j exp(-2(x-c_j)^2), s1 = sum_j j*e_j, s2 = sum_j j^2*e_j.
// Uniform-grid Gaussian sums == midpoint-rule integrals to O(step^2) ~ 6e-5 rel.
__device__ __forceinline__ void moments(float xv, float& s0, float& s1, float& s2) {
    const float h    = 1.0f / 255.0f;      // step/2
    const float invS = 127.5f;             // 1/step
    const float K    = 0.626657068658f;    // sqrt(pi/8)
    const float SQ2  = 1.41421356237f;

    float u1 = (1.0f + h) - xv;
    float u0 = (-1.0f - h) - xv;
    float A  = SQ2 * u1;
    float B  = SQ2 * u0;

    float I0 = K * (erff(A) - erff(B));
    float eA = __expf(-A * A);
    float eB = __expf(-B * B);
    float I1 = 0.25f * (eB - eA);
    float I2 = 0.25f * (u0 * eB - u1 * eA) + 0.25f * I0;

    float S0  = invS * I0;
    float Sc  = invS * fmaf(xv, I0, I1);
    float Scc = invS * (xv * xv * I0 + 2.0f * xv * I1 + I2);

    s0 = S0;
    s1 = invS * (Sc + S0);
    s2 = invS * invS * (Scc + 2.0f * Sc + S0);
}

// Fused: per-tile moments into LDS + all 8 (theta,d) pair sums -> per-block partials.
// combos 0..3: theta=0,  d={1,3,5,7}: Q=(r, w+d),   valid w<W-d
// combos 4..7: theta=45, d={1,2,4,6}: Q=(r-d, w+d), valid r>=d && w<W-d
__global__ __launch_bounds__(256) void fused_kernel(const float* __restrict__ x,
                                                    float* __restrict__ part) {
    __shared__ float ls0[LROWS][WW];
    __shared__ float ls1[LROWS][WW];
    __shared__ float ls2[LROWS][WW];
    __shared__ float sred[4][16];

    const int w     = threadIdx.x;          // column (lane = column -> stride-1 LDS)
    const int bx    = blockIdx.x;
    const int batch = blockIdx.y;
    const int r0    = bx * RPB;
    const float* xb = x + batch * NPIX;

    #pragma unroll
    for (int i = 0; i < LROWS; ++i) {
        int g = r0 - HALO + i;
        float s0 = 0.f, s1 = 0.f, s2 = 0.f;
        if (g >= 0) moments(xb[g * WW + w], s0, s1, s2);
        ls0[i][w] = s0; ls1[i][w] = s1; ls2[i][w] = s2;
    }
    __syncthreads();

    const int d0t[4]  = {1, 3, 5, 7};
    const int d45t[4] = {1, 2, 4, 6};
    float num[8] = {0,0,0,0,0,0,0,0};
    float den[8] = {0,0,0,0,0,0,0,0};

    #pragma unroll
    for (int rr = 0; rr < RPB; ++rr) {
        int lr = rr + HALO;
        int r  = r0 + rr;
        float P0 = ls0[lr][w], P1 = ls1[lr][w], P2 = ls2[lr][w];
        #pragma unroll
        for (int k = 0; k < 4; ++k) {
            int d = d0t[k];
            if (w < WW - d) {
                float Q0 = ls0[lr][w + d], Q1 = ls1[lr][w + d], Q2 = ls2[lr][w + d];
                den[k] = fmaf(P0, Q0, den[k]);
                num[k] = fmaf(P2, Q0, num[k]);
                num[k] = fmaf(P0, Q2, num[k]);
                num[k] = fmaf(-2.0f * P1, Q1, num[k]);
            }
        }
        #pragma unroll
        for (int k = 0; k < 4; ++k) {
            int d = d45t[k];
            if (r >= d && w < WW - d) {
                float Q0 = ls0[lr - d][w + d], Q1 = ls1[lr - d][w + d], Q2 = ls2[lr - d][w + d];
                den[k + 4] = fmaf(P0, Q0, den[k + 4]);
                num[k + 4] = fmaf(P2, Q0, num[k + 4]);
                num[k + 4] = fmaf(P0, Q2, num[k + 4]);
                num[k + 4] = fmaf(-2.0f * P1, Q1, num[k + 4]);
            }
        }
    }

    // wave(64) butterfly, then cross-wave combine via LDS
    #pragma unroll
    for (int off = 32; off > 0; off >>= 1) {
        #pragma unroll
        for (int k = 0; k < 8; ++k) {
            num[k] += __shfl_down(num[k], off);
            den[k] += __shfl_down(den[k], off);
        }
    }
    int lane = threadIdx.x & 63, wave = threadIdx.x >> 6;
    if (lane == 0) {
        #pragma unroll
        for (int k = 0; k < 8; ++k) { sred[wave][k] = num[k]; sred[wave][k + 8] = den[k]; }
    }
    __syncthreads();
    if (threadIdx.x < 16) {
        int k = threadIdx.x;
        float v = sred[0][k] + sred[1][k] + sred[2][k] + sred[3][k];
        int pair = (k & 7) * 4 + batch;
        int off  = (k < 8) ? 0 : NPAIR * NBX;
        part[off + pair * NBX + bx] = v;
    }
}

// Finalize: 4 lanes per output sum the 64 partials; theta90/135 are the closed-form constant.
__global__ void finalize_kernel(const float* __restrict__ part, float* __restrict__ out) {
    int t = threadIdx.x;          // 0..255
    int p = t >> 2;               // output index n = combo*4 + batch, 0..63
    int c = t & 3;                // chunk of 16 partials
    float num = 0.f, den = 0.f;
    if (p < NPAIR) {
        #pragma unroll
        for (int b = 0; b < 16; ++b) {
            num += part[p * NBX + c * 16 + b];
            den += part[NPAIR * NBX + p * NBX + c * 16 + b];
        }
    }
    num += __shfl_down(num, 2); num += __shfl_down(num, 1);
    den += __shfl_down(den, 2); den += __shfl_down(den, 1);
    if (c == 0) {
        // centers_b all -1 -> all bins equal -> contrast = sum_{jk}(j-k)^2 / L^2
        out[p] = (p < NPAIR) ? (num / den) : (float)(715816960.0 / 65536.0);
    }
}

extern "C" void kernel_launch(void* const* d_in, const int* in_sizes, int n_in,
                              void* d_out, int out_size, void* d_ws, size_t ws_size,
                              hipStream_t stream) {
    const float* x = (const float*)d_in[0];
    float* out = (float*)d_out;
    float* part = (float*)d_ws;   // 2 * NPAIR * NBX floats = 16 KiB, fully overwritten

    dim3 g1(NBX, NBATCH);
    fused_kernel<<<g1, 256, 0, stream>>>(x, part);
    finalize_kernel<<<1, 256, 0, stream>>>(part, out);
}